// Round 20
// baseline (144.806 us; speedup 1.0000x reference)
//
#include <hip/hip_runtime.h>

typedef __bf16 bf16x8 __attribute__((ext_vector_type(8)));
typedef __bf16 bf16x4 __attribute__((ext_vector_type(4)));
typedef float f32x4 __attribute__((ext_vector_type(4)));

#define D_MODEL 768
#define NH 12
#define DKH 64
#define BATCH 4
#define SEQ 2048
#define ROWS (BATCH*SEQ)   /* 8192 */
#define N_QKV (3*D_MODEL)  /* 2304 */
#define QSCALE 0.18033688f /* 0.125 * log2(e): folds softmax scale + exp2 domain into Q */

// raw v_exp_f32 (scores in [-1e30, ~40] need no ocml denormal guard)
__device__ __forceinline__ float fast_exp2(float x) {
  float r;
  asm("v_exp_f32 %0, %1" : "=v"(r) : "v"(x));
  return r;
}

// ---------------- convert fp32 -> bf16 (vectorized 8B stores) ----------------
__global__ void k_convert(const float* __restrict__ in, __bf16* __restrict__ out, int n) {
  int i = (blockIdx.x * blockDim.x + threadIdx.x) * 4;
  if (i >= n) return;
  float4 v = *(const float4*)(in + i);
  bf16x4 o4 = {(__bf16)v.x, (__bf16)v.y, (__bf16)v.z, (__bf16)v.w};
  *(bf16x4*)(out + i) = o4;
}

// ---------------- transpose fp32 [R][C] -> bf16 [C][R] ----------------
__global__ void k_transpose(const float* __restrict__ in, __bf16* __restrict__ out, int R, int C) {
  __shared__ float tile[32][33];
  int c0 = blockIdx.x * 32, r0 = blockIdx.y * 32;
  int tx = threadIdx.x, ty = threadIdx.y;   // (32, 8)
  #pragma unroll
  for (int i = 0; i < 4; ++i) {
    int r = ty + i*8;
    tile[r][tx] = in[(size_t)(r0 + r)*C + c0 + tx];
  }
  __syncthreads();
  #pragma unroll
  for (int i = 0; i < 4; ++i) {
    int c = ty + i*8;
    out[(size_t)(c0 + c)*R + r0 + tx] = (__bf16)tile[tx][c];
  }
}

// ================= 128x128 core (GEMM3) — proven R14 structure =================
__device__ __forceinline__ void gemm_stage(const __bf16* __restrict__ A, int lda,
                                           const __bf16* __restrict__ Bt, int ldb,
                                           int m0, int n0, int kt,
                                           __bf16* lA, __bf16* lB) {
  const int tid  = threadIdx.x;
  const int lane = tid & 63;
  const int wid  = tid >> 6;
  #pragma unroll
  for (int c = 0; c < 2; ++c) {
    int chunk = wid*2 + c;               // 0..7
    int bo = chunk*1024 + lane*16;
    int m  = bo >> 6;
    int kb = ((bo & 63) ^ (((m >> 1) & 3) << 4)) >> 1;
    __builtin_amdgcn_global_load_lds(
      (const __attribute__((address_space(1))) void*)(A + (size_t)(m0 + m)*lda + kt + kb),
      (__attribute__((address_space(3))) void*)(lA + chunk*512), 16, 0, 0);
    __builtin_amdgcn_global_load_lds(
      (const __attribute__((address_space(1))) void*)(Bt + (size_t)(n0 + m)*ldb + kt + kb),
      (__attribute__((address_space(3))) void*)(lB + chunk*512), 16, 0, 0);
  }
}

__device__ __forceinline__ void gemm_iter(const __bf16* __restrict__ A, int lda,
                                          const __bf16* __restrict__ Bt, int ldb,
                                          int m0, int n0, int t, int NT,
                                          __bf16* lA, __bf16* lB, int BUF, int NBUF,
                                          int wm, int wn, int lr, int lk,
                                          f32x4 acc[4][4]) {
  if (t + 1 < NT) asm volatile("s_waitcnt vmcnt(4)" ::: "memory");
  else            asm volatile("s_waitcnt vmcnt(0)" ::: "memory");
  __builtin_amdgcn_s_barrier();
  asm volatile("" ::: "memory");
  if (t + 2 < NT)
    gemm_stage(A, lda, Bt, ldb, m0, n0, (t+2)*32, lA + NBUF*4096, lB + NBUF*4096);
  const char* cA = (const char*)(lA + BUF*4096);
  const char* cB = (const char*)(lB + BUF*4096);
  bf16x8 af[4], bfr[4];
  #pragma unroll
  for (int i = 0; i < 4; ++i) {
    int ra = wm + i*16 + lr;
    int rb = wn + i*16 + lr;
    af[i]  = *(const bf16x8*)(cA + ra*64 + ((lk*16) ^ (((ra >> 1) & 3) << 4)));
    bfr[i] = *(const bf16x8*)(cB + rb*64 + ((lk*16) ^ (((rb >> 1) & 3) << 4)));
  }
  #pragma unroll
  for (int mi = 0; mi < 4; ++mi)
    #pragma unroll
    for (int ni = 0; ni < 4; ++ni)
      acc[mi][ni] = __builtin_amdgcn_mfma_f32_16x16x32_bf16(af[mi], bfr[ni], acc[mi][ni], 0, 0, 0);
}

__device__ __forceinline__ void gemm_core(const __bf16* __restrict__ A, int lda,
                                          const __bf16* __restrict__ Bt, int ldb,
                                          int K, int m0, int n0,
                                          __bf16* lA, __bf16* lB, f32x4 acc[4][4]) {
  const int lane = threadIdx.x & 63;
  const int wid  = threadIdx.x >> 6;
  const int wm   = (wid >> 1) * 64;
  const int wn   = (wid & 1) * 64;
  const int lr   = lane & 15;
  const int lk   = lane >> 4;
  const int NT   = K >> 5;

  gemm_stage(A, lda, Bt, ldb, m0, n0, 0,  lA,        lB);
  gemm_stage(A, lda, Bt, ldb, m0, n0, 32, lA + 4096, lB + 4096);

  for (int t = 0; t < NT; t += 3) {
    gemm_iter(A, lda, Bt, ldb, m0, n0, t,   NT, lA, lB, 0, 2, wm, wn, lr, lk, acc);
    gemm_iter(A, lda, Bt, ldb, m0, n0, t+1, NT, lA, lB, 1, 0, wm, wn, lr, lk, acc);
    gemm_iter(A, lda, Bt, ldb, m0, n0, t+2, NT, lA, lB, 2, 1, wm, wn, lr, lk, acc);
  }
}

// ================= 128x256 core (GEMM1) — 32 MFMA per barrier =================
// A-tile 128x32 (8KB), B-tile 256x32 (16KB) per buffer; 6 loads/wave/stage.
__device__ __forceinline__ void gemm_stage2(const __bf16* __restrict__ A, int lda,
                                            const __bf16* __restrict__ Bt, int ldb,
                                            int m0, int n0, int kt,
                                            __bf16* lA, __bf16* lB) {
  const int tid  = threadIdx.x;
  const int lane = tid & 63;
  const int wid  = tid >> 6;
  #pragma unroll
  for (int c = 0; c < 2; ++c) {        // A: 8 chunks
    int chunk = wid*2 + c;
    int bo = chunk*1024 + lane*16;
    int m  = bo >> 6;
    int kb = ((bo & 63) ^ (((m >> 1) & 3) << 4)) >> 1;
    __builtin_amdgcn_global_load_lds(
      (const __attribute__((address_space(1))) void*)(A + (size_t)(m0 + m)*lda + kt + kb),
      (__attribute__((address_space(3))) void*)(lA + chunk*512), 16, 0, 0);
  }
  #pragma unroll
  for (int c = 0; c < 4; ++c) {        // B: 16 chunks
    int chunk = wid*4 + c;
    int bo = chunk*1024 + lane*16;
    int m  = bo >> 6;                  // rows 0..255
    int kb = ((bo & 63) ^ (((m >> 1) & 3) << 4)) >> 1;
    __builtin_amdgcn_global_load_lds(
      (const __attribute__((address_space(1))) void*)(Bt + (size_t)(n0 + m)*ldb + kt + kb),
      (__attribute__((address_space(3))) void*)(lB + chunk*512), 16, 0, 0);
  }
}

__device__ __forceinline__ void gemm_iter2(const __bf16* __restrict__ A, int lda,
                                           const __bf16* __restrict__ Bt, int ldb,
                                           int m0, int n0, int t, int NT,
                                           __bf16* lA, __bf16* lB, int BUF, int NBUF,
                                           int wm, int wn, int lr, int lk,
                                           f32x4 acc[4][8]) {
  if (t + 1 < NT) asm volatile("s_waitcnt vmcnt(6)" ::: "memory");
  else            asm volatile("s_waitcnt vmcnt(0)" ::: "memory");
  __builtin_amdgcn_s_barrier();
  asm volatile("" ::: "memory");
  if (t + 2 < NT)
    gemm_stage2(A, lda, Bt, ldb, m0, n0, (t+2)*32, lA + NBUF*4096, lB + NBUF*8192);
  const char* cA = (const char*)(lA + BUF*4096);
  const char* cB = (const char*)(lB + BUF*8192);
  bf16x8 af[4], bfr[8];
  #pragma unroll
  for (int i = 0; i < 4; ++i) {
    int ra = wm + i*16 + lr;
    af[i]  = *(const bf16x8*)(cA + ra*64 + ((lk*16) ^ (((ra >> 1) & 3) << 4)));
  }
  #pragma unroll
  for (int i = 0; i < 8; ++i) {
    int rb = wn + i*16 + lr;
    bfr[i] = *(const bf16x8*)(cB + rb*64 + ((lk*16) ^ (((rb >> 1) & 3) << 4)));
  }
  #pragma unroll
  for (int mi = 0; mi < 4; ++mi)
    #pragma unroll
    for (int ni = 0; ni < 8; ++ni)
      acc[mi][ni] = __builtin_amdgcn_mfma_f32_16x16x32_bf16(af[mi], bfr[ni], acc[mi][ni], 0, 0, 0);
}

__device__ __forceinline__ void gemm_core2(const __bf16* __restrict__ A, int lda,
                                           const __bf16* __restrict__ Bt, int ldb,
                                           int K, int m0, int n0,
                                           __bf16* lA, __bf16* lB, f32x4 acc[4][8]) {
  const int lane = threadIdx.x & 63;
  const int wid  = threadIdx.x >> 6;
  const int wm   = (wid >> 1) * 64;
  const int wn   = (wid & 1) * 128;
  const int lr   = lane & 15;
  const int lk   = lane >> 4;
  const int NT   = K >> 5;            // 24, divisible by 3

  gemm_stage2(A, lda, Bt, ldb, m0, n0, 0,  lA,        lB);
  gemm_stage2(A, lda, Bt, ldb, m0, n0, 32, lA + 4096, lB + 8192);

  for (int t = 0; t < NT; t += 3) {
    gemm_iter2(A, lda, Bt, ldb, m0, n0, t,   NT, lA, lB, 0, 2, wm, wn, lr, lk, acc);
    gemm_iter2(A, lda, Bt, ldb, m0, n0, t+1, NT, lA, lB, 1, 0, wm, wn, lr, lk, acc);
    gemm_iter2(A, lda, Bt, ldb, m0, n0, t+2, NT, lA, lB, 2, 1, wm, wn, lr, lk, acc);
  }
}

// ---------------- GEMM1: qkv = xb @ WqkvT + bqkv, scatter to Q(scaled),K,V^T(pi) ----------------
// 128x256 tile; tt block-uniform (768 = 3*256). Wave tile 64x128 (2 heads for V).
__global__ __launch_bounds__(256) void k_gemm_qkv(const __bf16* __restrict__ xb,
                                                  const __bf16* __restrict__ wT,
                                                  const float* __restrict__ bias,
                                                  __bf16* __restrict__ qb,
                                                  __bf16* __restrict__ kb,
                                                  __bf16* __restrict__ vtb) {
  __shared__ __align__(16) __bf16 lA[3*128*32];   // 24KB
  __shared__ __align__(16) __bf16 lB[3*256*32];   // 48KB
  f32x4 acc[4][8];
  #pragma unroll
  for (int i = 0; i < 4; ++i)
    #pragma unroll
    for (int j = 0; j < 8; ++j) { f32x4 z = {0.f,0.f,0.f,0.f}; acc[i][j] = z; }

  const int GX = N_QKV/256;  // 9
  int bid = blockIdx.y * GX + blockIdx.x;
  int cpx = (GX * ROWS/128) >> 3;       // 576/8 = 72
  int swz = (bid & 7) * cpx + (bid >> 3);
  const int m0 = (swz / GX) * 128, n0 = (swz % GX) * 256;
  gemm_core2(xb, D_MODEL, wT, D_MODEL, D_MODEL, m0, n0, lA, lB, acc);

  const int lane = threadIdx.x & 63;
  const int wid  = threadIdx.x >> 6;
  const int wm = (wid >> 1) * 64, wn = (wid & 1) * 128;
  const int lr = lane & 15, lk = lane >> 4;
  const int tt = n0 / D_MODEL;           // block-uniform q/k/v selector

  if (tt < 2) {
    #pragma unroll
    for (int mi = 0; mi < 4; ++mi) {
      #pragma unroll
      for (int ni = 0; ni < 8; ++ni) {
        int col = n0 + wn + ni*16 + lr;
        int r2  = col - tt*D_MODEL;
        int hh  = r2 >> 6, dk = r2 & 63;
        float bv = bias[col];
        #pragma unroll
        for (int j = 0; j < 4; ++j) {
          int row = m0 + wm + mi*16 + lk*4 + j;
          int bb = row >> 11, ss = row & 2047;
          float fv = acc[mi][ni][j] + bv;
          if (tt == 0) qb[(((size_t)bb*NH + hh)*SEQ + ss)*DKH + dk] = (__bf16)(fv * QSCALE);
          else         kb[(((size_t)bb*NH + hh)*SEQ + ss)*DKH + dk] = (__bf16)fv;
        }
      }
    }
  } else {
    // V: per-wave private 8KB patch in lB; two 64x64 head-patches sequentially.
    __syncthreads();   // all waves past their last tile-buf reads
    __bf16* patch = lB + wid*4096;
    int bb  = m0 >> 11;
    int ssG = (m0 & 2047) + wm;
    int dk_h = lane >> 4;
    int pb   = (lane & 15) * 4;
    int g    = pb >> 5;
    int tq   = (pb >> 2) & 7;
    int rwb  = g*32 + 16*(tq & 1) + 4*(tq >> 1);
    #pragma unroll
    for (int hh2 = 0; hh2 < 2; ++hh2) {
      #pragma unroll
      for (int ni2 = 0; ni2 < 4; ++ni2) {
        int cl = ni2*16 + lr;
        float bv = bias[n0 + wn + hh2*64 + cl];
        int sw2 = (cl & 7) << 4;
        #pragma unroll
        for (int mi = 0; mi < 4; ++mi) {
          bf16x4 v4;
          #pragma unroll
          for (int j = 0; j < 4; ++j) v4[j] = (__bf16)(acc[mi][hh2*4 + ni2][j] + bv);
          *(bf16x4*)((char*)patch + ((cl*128 + (mi*16 + lk*4)*2) ^ sw2)) = v4;
        }
      }
      int hh = (n0 + wn + hh2*64 - 2*D_MODEL) >> 6;   // wave-uniform
      __bf16* vout = vtb + (((size_t)bb*NH + hh)*DKH)*SEQ + ssG + pb;
      #pragma unroll
      for (int r = 0; r < 16; ++r) {
        int dk = r*4 + dk_h;
        bf16x4 v4 = *(const bf16x4*)((const char*)patch + ((dk*128 + rwb*2) ^ ((dk & 7) << 4)));
        *(bf16x4*)(vout + (size_t)dk*SEQ) = v4;
      }
    }
  }
}

// ---------------- GEMM3: out = attn @ WoutT + bout (fp32 out) ----------------
__global__ __launch_bounds__(256) void k_gemm_out(const __bf16* __restrict__ ab,
                                                  const __bf16* __restrict__ wT,
                                                  const float* __restrict__ bias,
                                                  float* __restrict__ out) {
  __shared__ __align__(16) __bf16 lA[3*128*32];
  __shared__ __align__(16) __bf16 lB[3*128*32];
  f32x4 acc[4][4];
  #pragma unroll
  for (int i = 0; i < 4; ++i)
    #pragma unroll
    for (int j = 0; j < 4; ++j) { f32x4 z = {0.f,0.f,0.f,0.f}; acc[i][j] = z; }

  const int GX = D_MODEL/128;  // 6
  int bid = blockIdx.y * GX + blockIdx.x;
  int cpx = (GX * ROWS/128) >> 3;
  int swz = (bid & 7) * cpx + (bid >> 3);
  const int m0 = (swz / GX) * 128, n0 = (swz % GX) * 128;
  gemm_core(ab, D_MODEL, wT, D_MODEL, D_MODEL, m0, n0, lA, lB, acc);

  const int lane = threadIdx.x & 63;
  const int wid  = threadIdx.x >> 6;
  const int wm = (wid >> 1) * 64, wn = (wid & 1) * 64;
  const int lr = lane & 15, lk = lane >> 4;
  #pragma unroll
  for (int mi = 0; mi < 4; ++mi) {
    #pragma unroll
    for (int ni = 0; ni < 4; ++ni) {
      int col = n0 + wn + ni*16 + lr;
      float bv = bias[col];
      #pragma unroll
      for (int j = 0; j < 4; ++j) {
        int row = m0 + wm + mi*16 + lk*4 + j;
        out[(size_t)row*D_MODEL + col] = acc[mi][ni][j] + bv;
      }
    }
  }
}

// ---------------- Flash attention (causal), 4 waves x 16 q-rows, LPT + backfill ----
// No-max softmax; raw v_exp_f32. (R19 proven, unchanged.)
__global__ __launch_bounds__(256) void k_attn(const __bf16* __restrict__ q,
                                              const __bf16* __restrict__ k,
                                              const __bf16* __restrict__ vt,
                                              __bf16* __restrict__ out) {
  __shared__ __align__(16) char lsK[2][8192];
  __shared__ __align__(16) char lsV[2][8192];

  const int tid  = threadIdx.x;
  const int lane = tid & 63;
  const int wid  = tid >> 6;
  const int lr   = lane & 15;
  const int lk   = lane >> 4;

  const int bid  = blockIdx.x;
  const int qi64 = 31 - bid / (BATCH*NH);
  const int bh   = bid % (BATCH*NH);
  const int b    = bh / NH, h = bh - b*NH;
  const int q0w  = qi64*64 + wid*16;
  const int nt   = qi64 + 1;

  const __bf16* qh = q + (size_t)bh*SEQ*DKH;
  const char*   kB = (const char*)(k  + (size_t)bh*SEQ*DKH);
  const char*   vB = (const char*)(vt + (size_t)bh*DKH*SEQ);

  bf16x8 bq[2];
  #pragma unroll
  for (int c = 0; c < 2; ++c)
    bq[c] = *(const bf16x8*)(qh + (size_t)(q0w + lr)*DKH + c*32 + lk*8);

  bf16x8 ones;
  #pragma unroll
  for (int i = 0; i < 8; ++i) ones[i] = (__bf16)1.0f;
  const f32x4 Z4 = {0.f, 0.f, 0.f, 0.f};

  const int offB = lr*128 + ((lk*16) ^ ((lr & 7) << 4));

  f32x4 o[4];
  #pragma unroll
  for (int df = 0; df < 4; ++df) { f32x4 z = {0.f,0.f,0.f,0.f}; o[df] = z; }
  f32x4 o_l = {0.f, 0.f, 0.f, 0.f};

  auto stage = [&](int buf, int kv0) {
    #pragma unroll
    for (int c = 0; c < 2; ++c) {
      int lb   = (wid*2 + c)*1024 + lane*16;
      int row  = lb >> 7;
      int colb = (lb & 127) ^ ((row & 7) << 4);
      __builtin_amdgcn_global_load_lds(
        (const __attribute__((address_space(1))) void*)(kB + (size_t)(kv0 + row)*128 + colb),
        (__attribute__((address_space(3))) void*)(lsK[buf] + (wid*2 + c)*1024), 16, 0, 0);
      __builtin_amdgcn_global_load_lds(
        (const __attribute__((address_space(1))) void*)(vB + (size_t)row*(SEQ*2) + (size_t)kv0*2 + colb),
        (__attribute__((address_space(3))) void*)(lsV[buf] + (wid*2 + c)*1024), 16, 0, 0);
    }
  };

  stage(0, 0);
  __syncthreads();
  int cur = 0;

  for (int t = 0; t < nt; ++t) {
    const int kv0 = t * 64;
    if (t + 1 < nt) stage(cur ^ 1, kv0 + 64);

    {
      const char* kp0 = lsK[cur] + offB;
      const char* kp1 = lsK[cur] + (offB ^ 64);
      const char* vp0 = lsV[cur] + offB;
      const char* vp1 = lsV[cur] + (offB ^ 64);

      f32x4 sc[4];
      __builtin_amdgcn_s_setprio(1);
      #pragma unroll
      for (int n = 0; n < 4; ++n) {
        bf16x8 ak0 = *(const bf16x8*)(kp0 + n*2048);
        bf16x8 ak1 = *(const bf16x8*)(kp1 + n*2048);
        sc[n] = __builtin_amdgcn_mfma_f32_16x16x32_bf16(ak0, bq[0], Z4, 0, 0, 0);
        sc[n] = __builtin_amdgcn_mfma_f32_16x16x32_bf16(ak1, bq[1], sc[n], 0, 0, 0);
      }
      __builtin_amdgcn_s_setprio(0);
      if (kv0 + 63 > q0w) {
        int qrow = q0w + lr;
        #pragma unroll
        for (int n = 0; n < 4; ++n) {
          int kvb = kv0 + n*16 + lk*4;
          #pragma unroll
          for (int j = 0; j < 4; ++j)
            if (kvb + j > qrow) sc[n][j] = -1e30f;
        }
      }
      bf16x8 pa[2];
      #pragma unroll
      for (int n = 0; n < 4; ++n)
        #pragma unroll
        for (int j = 0; j < 4; ++j)
          pa[n >> 1][((n & 1) << 2) | j] = (__bf16)fast_exp2(sc[n][j]);
      __builtin_amdgcn_s_setprio(1);
      o_l = __builtin_amdgcn_mfma_f32_16x16x32_bf16(pa[0], ones, o_l, 0, 0, 0);
      o_l = __builtin_amdgcn_mfma_f32_16x16x32_bf16(pa[1], ones, o_l, 0, 0, 0);
      #pragma unroll
      for (int df = 0; df < 4; ++df) {
        bf16x8 bv0 = *(const bf16x8*)(vp0 + df*2048);
        bf16x8 bv1 = *(const bf16x8*)(vp1 + df*2048);
        o[df] = __builtin_amdgcn_mfma_f32_16x16x32_bf16(pa[0], bv0, o[df], 0, 0, 0);
        o[df] = __builtin_amdgcn_mfma_f32_16x16x32_bf16(pa[1], bv1, o[df], 0, 0, 0);
      }
      __builtin_amdgcn_s_setprio(0);
    }
    __syncthreads();
    cur ^= 1;
  }

  float invl[4];
  #pragma unroll
  for (int j = 0; j < 4; ++j) invl[j] = 1.0f / o_l[j];
  #pragma unroll
  for (int df = 0; df < 4; ++df) {
    int d = df*16 + lr;
    #pragma unroll
    for (int j = 0; j < 4; ++j) {
      int ss = q0w + lk*4 + j;
      out[((size_t)b*SEQ + ss)*D_MODEL + h*DKH + d] = (__bf16)(o[df][j] * invl[j]);
    }
  }
}

// ---------------- launch ----------------
extern "C" void kernel_launch(void* const* d_in, const int* in_sizes, int n_in,
                              void* d_out, int out_size, void* d_ws, size_t ws_size,
                              hipStream_t stream) {
  const float* x    = (const float*)d_in[0];
  /* d_in[1] = causal mask, implemented analytically */
  const float* Wqkv = (const float*)d_in[2];
  const float* bqkv = (const float*)d_in[3];
  const float* Wout = (const float*)d_in[4];
  const float* bout = (const float*)d_in[5];
  float* out = (float*)d_out;

  char* w = (char*)d_ws;
  __bf16* xb    = (__bf16*)w; w += (size_t)ROWS*D_MODEL*2;
  __bf16* wqkvT = (__bf16*)w; w += (size_t)N_QKV*D_MODEL*2;
  __bf16* woutT = (__bf16*)w; w += (size_t)D_MODEL*D_MODEL*2;
  __bf16* qb    = (__bf16*)w; w += (size_t)BATCH*NH*SEQ*DKH*2;
  __bf16* kb    = (__bf16*)w; w += (size_t)BATCH*NH*SEQ*DKH*2;
  __bf16* vtb   = (__bf16*)w; w += (size_t)BATCH*NH*SEQ*DKH*2;
  __bf16* attnb = (__bf16*)w; w += (size_t)ROWS*D_MODEL*2;

  k_convert<<<(ROWS*D_MODEL/4 + 255)/256, 256, 0, stream>>>(x, xb, ROWS*D_MODEL);
  k_transpose<<<dim3(N_QKV/32, D_MODEL/32), dim3(32, 8), 0, stream>>>(Wqkv, wqkvT, D_MODEL, N_QKV);
  k_transpose<<<dim3(D_MODEL/32, D_MODEL/32), dim3(32, 8), 0, stream>>>(Wout, woutT, D_MODEL, D_MODEL);
  k_gemm_qkv<<<dim3(N_QKV/256, ROWS/128), 256, 0, stream>>>(xb, wqkvT, bqkv, qb, kb, vtb);
  k_attn<<<32*BATCH*NH, 256, 0, stream>>>(qb, kb, vtb, attnb);
  k_gemm_out<<<dim3(D_MODEL/128, ROWS/128), 256, 0, stream>>>(attnb, woutT, bout, out);
}

// Round 21
// 126.448 us; speedup vs baseline: 1.1452x; 1.1452x over previous
//
#include <hip/hip_runtime.h>

typedef __bf16 bf16x8 __attribute__((ext_vector_type(8)));
typedef __bf16 bf16x4 __attribute__((ext_vector_type(4)));
typedef float f32x4 __attribute__((ext_vector_type(4)));

#define D_MODEL 768
#define NH 12
#define DKH 64
#define BATCH 4
#define SEQ 2048
#define ROWS (BATCH*SEQ)   /* 8192 */
#define N_QKV (3*D_MODEL)  /* 2304 */
#define QSCALE 0.18033688f /* 0.125 * log2(e): folds softmax scale + exp2 domain into Q */

// raw v_exp_f32 (scores in [-1e30, ~40] need no ocml denormal guard)
__device__ __forceinline__ float fast_exp2(float x) {
  float r;
  asm("v_exp_f32 %0, %1" : "=v"(r) : "v"(x));
  return r;
}

// ---------------- convert fp32 -> bf16 (vectorized 8B stores) ----------------
__global__ void k_convert(const float* __restrict__ in, __bf16* __restrict__ out, int n) {
  int i = (blockIdx.x * blockDim.x + threadIdx.x) * 4;
  if (i >= n) return;
  float4 v = *(const float4*)(in + i);
  bf16x4 o4 = {(__bf16)v.x, (__bf16)v.y, (__bf16)v.z, (__bf16)v.w};
  *(bf16x4*)(out + i) = o4;
}

// ---------------- fused transpose: Wqkv [768][2304] -> [2304][768] bf16
//                  and Wout [768][768] -> [768][768]^T bf16, one launch ----------------
__global__ void k_transpose2(const float* __restrict__ wqkv, __bf16* __restrict__ wqkvT,
                             const float* __restrict__ wout, __bf16* __restrict__ woutT) {
  __shared__ float tile[32][33];
  const int NB1 = (N_QKV/32) * (D_MODEL/32);   // 72*24 = 1728 blocks for Wqkv
  int bb = blockIdx.x;
  const float* in; __bf16* out; int R, C, bx, by;
  if (bb < NB1) { in = wqkv; out = wqkvT; R = D_MODEL; C = N_QKV;  bx = bb % (N_QKV/32);  by = bb / (N_QKV/32); }
  else { bb -= NB1; in = wout; out = woutT; R = D_MODEL; C = D_MODEL; bx = bb % (D_MODEL/32); by = bb / (D_MODEL/32); }
  int c0 = bx * 32, r0 = by * 32;
  int tx = threadIdx.x, ty = threadIdx.y;   // (32, 8)
  #pragma unroll
  for (int i = 0; i < 4; ++i) {
    int r = ty + i*8;
    tile[r][tx] = in[(size_t)(r0 + r)*C + c0 + tx];
  }
  __syncthreads();
  #pragma unroll
  for (int i = 0; i < 4; ++i) {
    int c = ty + i*8;
    out[(size_t)(c0 + c)*R + r0 + tx] = (__bf16)tile[tx][c];
  }
}

// ================= 128x128 GEMM core: triple-buffer counted-vmcnt =================
__device__ __forceinline__ void gemm_stage(const __bf16* __restrict__ A, int lda,
                                           const __bf16* __restrict__ Bt, int ldb,
                                           int m0, int n0, int kt,
                                           __bf16* lA, __bf16* lB) {
  const int tid  = threadIdx.x;
  const int lane = tid & 63;
  const int wid  = tid >> 6;
  #pragma unroll
  for (int c = 0; c < 2; ++c) {
    int chunk = wid*2 + c;               // 0..7
    int bo = chunk*1024 + lane*16;
    int m  = bo >> 6;
    int kb = ((bo & 63) ^ (((m >> 1) & 3) << 4)) >> 1;
    __builtin_amdgcn_global_load_lds(
      (const __attribute__((address_space(1))) void*)(A + (size_t)(m0 + m)*lda + kt + kb),
      (__attribute__((address_space(3))) void*)(lA + chunk*512), 16, 0, 0);
    __builtin_amdgcn_global_load_lds(
      (const __attribute__((address_space(1))) void*)(Bt + (size_t)(n0 + m)*ldb + kt + kb),
      (__attribute__((address_space(3))) void*)(lB + chunk*512), 16, 0, 0);
  }
}

__device__ __forceinline__ void gemm_iter(const __bf16* __restrict__ A, int lda,
                                          const __bf16* __restrict__ Bt, int ldb,
                                          int m0, int n0, int t, int NT,
                                          __bf16* lA, __bf16* lB, int BUF, int NBUF,
                                          int wm, int wn, int lr, int lk,
                                          f32x4 acc[4][4]) {
  if (t + 1 < NT) asm volatile("s_waitcnt vmcnt(4)" ::: "memory");
  else            asm volatile("s_waitcnt vmcnt(0)" ::: "memory");
  __builtin_amdgcn_s_barrier();
  asm volatile("" ::: "memory");
  if (t + 2 < NT)
    gemm_stage(A, lda, Bt, ldb, m0, n0, (t+2)*32, lA + NBUF*4096, lB + NBUF*4096);
  const char* cA = (const char*)(lA + BUF*4096);
  const char* cB = (const char*)(lB + BUF*4096);
  bf16x8 af[4], bfr[4];
  #pragma unroll
  for (int i = 0; i < 4; ++i) {
    int ra = wm + i*16 + lr;
    int rb = wn + i*16 + lr;
    af[i]  = *(const bf16x8*)(cA + ra*64 + ((lk*16) ^ (((ra >> 1) & 3) << 4)));
    bfr[i] = *(const bf16x8*)(cB + rb*64 + ((lk*16) ^ (((rb >> 1) & 3) << 4)));
  }
  #pragma unroll
  for (int mi = 0; mi < 4; ++mi)
    #pragma unroll
    for (int ni = 0; ni < 4; ++ni)
      acc[mi][ni] = __builtin_amdgcn_mfma_f32_16x16x32_bf16(af[mi], bfr[ni], acc[mi][ni], 0, 0, 0);
}

__device__ __forceinline__ void gemm_core(const __bf16* __restrict__ A, int lda,
                                          const __bf16* __restrict__ Bt, int ldb,
                                          int K, int m0, int n0,
                                          __bf16* lA, __bf16* lB, f32x4 acc[4][4]) {
  const int lane = threadIdx.x & 63;
  const int wid  = threadIdx.x >> 6;
  const int wm   = (wid >> 1) * 64;
  const int wn   = (wid & 1) * 64;
  const int lr   = lane & 15;
  const int lk   = lane >> 4;
  const int NT   = K >> 5;

  gemm_stage(A, lda, Bt, ldb, m0, n0, 0,  lA,        lB);
  gemm_stage(A, lda, Bt, ldb, m0, n0, 32, lA + 4096, lB + 4096);

  for (int t = 0; t < NT; t += 3) {
    gemm_iter(A, lda, Bt, ldb, m0, n0, t,   NT, lA, lB, 0, 2, wm, wn, lr, lk, acc);
    gemm_iter(A, lda, Bt, ldb, m0, n0, t+1, NT, lA, lB, 1, 0, wm, wn, lr, lk, acc);
    gemm_iter(A, lda, Bt, ldb, m0, n0, t+2, NT, lA, lB, 2, 1, wm, wn, lr, lk, acc);
  }
}

// ---------------- GEMM1: qkv = xb @ WqkvT + bqkv, scatter to Q(scaled),K,V^T(pi) ----------------
__global__ __launch_bounds__(256) void k_gemm_qkv(const __bf16* __restrict__ xb,
                                                  const __bf16* __restrict__ wT,
                                                  const float* __restrict__ bias,
                                                  __bf16* __restrict__ qb,
                                                  __bf16* __restrict__ kb,
                                                  __bf16* __restrict__ vtb) {
  __shared__ __align__(16) __bf16 lA[3*128*32];
  __shared__ __align__(16) __bf16 lB[3*128*32];
  f32x4 acc[4][4];
  #pragma unroll
  for (int i = 0; i < 4; ++i)
    #pragma unroll
    for (int j = 0; j < 4; ++j) { f32x4 z = {0.f,0.f,0.f,0.f}; acc[i][j] = z; }

  const int GX = N_QKV/128;  // 18
  int bid = blockIdx.y * GX + blockIdx.x;
  int cpx = (GX * ROWS/128) >> 3;
  int swz = (bid & 7) * cpx + (bid >> 3);
  const int m0 = (swz / GX) * 128, n0 = (swz % GX) * 128;
  gemm_core(xb, D_MODEL, wT, D_MODEL, D_MODEL, m0, n0, lA, lB, acc);

  const int lane = threadIdx.x & 63;
  const int wid  = threadIdx.x >> 6;
  const int wm = (wid >> 1) * 64, wn = (wid & 1) * 64;
  const int lr = lane & 15, lk = lane >> 4;
  const int tt = n0 / D_MODEL;           // block-uniform q/k/v selector

  if (tt < 2) {
    #pragma unroll
    for (int mi = 0; mi < 4; ++mi) {
      #pragma unroll
      for (int ni = 0; ni < 4; ++ni) {
        int col = n0 + wn + ni*16 + lr;
        int r2  = col - tt*D_MODEL;
        int hh  = r2 >> 6, dk = r2 & 63;
        float bv = bias[col];
        #pragma unroll
        for (int j = 0; j < 4; ++j) {
          int row = m0 + wm + mi*16 + lk*4 + j;
          int bb = row >> 11, ss = row & 2047;
          float fv = acc[mi][ni][j] + bv;
          if (tt == 0) qb[(((size_t)bb*NH + hh)*SEQ + ss)*DKH + dk] = (__bf16)(fv * QSCALE);
          else         kb[(((size_t)bb*NH + hh)*SEQ + ss)*DKH + dk] = (__bf16)fv;
        }
      }
    }
  } else {
    // V: per-wave 8KB LDS patch, then pi-folded transposed read-back.
    __syncthreads();   // all waves past their last tile-buf reads
    __bf16* patch = (wid < 2 ? lA : lB) + (wid & 1)*4096;
    #pragma unroll
    for (int ni = 0; ni < 4; ++ni) {
      int cl = ni*16 + lr;
      float bv = bias[n0 + wn + cl];
      int sw2 = (cl & 7) << 4;
      #pragma unroll
      for (int mi = 0; mi < 4; ++mi) {
        bf16x4 v4;
        #pragma unroll
        for (int j = 0; j < 4; ++j) v4[j] = (__bf16)(acc[mi][ni][j] + bv);
        *(bf16x4*)((char*)patch + ((cl*128 + (mi*16 + lk*4)*2) ^ sw2)) = v4;
      }
    }
    int hh   = (n0 + wn - 2*D_MODEL) >> 6;   // wave-uniform
    int bb   = m0 >> 11;
    int ssG  = (m0 & 2047) + wm;             // granule-aligned base
    int dk_h = lane >> 4;                    // 0..3
    int pb   = (lane & 15) * 4;              // p = pb..pb+3
    int g    = pb >> 5;                      // granule 0/1
    int tq   = (pb >> 2) & 7;
    int rwb  = g*32 + 16*(tq & 1) + 4*(tq >> 1);   // source kv offset (pi)
    __bf16* vout = vtb + (((size_t)bb*NH + hh)*DKH)*SEQ + ssG + pb;
    #pragma unroll
    for (int r = 0; r < 16; ++r) {
      int dk = r*4 + dk_h;
      bf16x4 v4 = *(const bf16x4*)((const char*)patch + ((dk*128 + rwb*2) ^ ((dk & 7) << 4)));
      *(bf16x4*)(vout + (size_t)dk*SEQ) = v4;
    }
  }
}

// ---------------- GEMM3: out = attn @ WoutT + bout (fp32 out) ----------------
__global__ __launch_bounds__(256) void k_gemm_out(const __bf16* __restrict__ ab,
                                                  const __bf16* __restrict__ wT,
                                                  const float* __restrict__ bias,
                                                  float* __restrict__ out) {
  __shared__ __align__(16) __bf16 lA[3*128*32];
  __shared__ __align__(16) __bf16 lB[3*128*32];
  f32x4 acc[4][4];
  #pragma unroll
  for (int i = 0; i < 4; ++i)
    #pragma unroll
    for (int j = 0; j < 4; ++j) { f32x4 z = {0.f,0.f,0.f,0.f}; acc[i][j] = z; }

  const int GX = D_MODEL/128;  // 6
  int bid = blockIdx.y * GX + blockIdx.x;
  int cpx = (GX * ROWS/128) >> 3;
  int swz = (bid & 7) * cpx + (bid >> 3);
  const int m0 = (swz / GX) * 128, n0 = (swz % GX) * 128;
  gemm_core(ab, D_MODEL, wT, D_MODEL, D_MODEL, m0, n0, lA, lB, acc);

  const int lane = threadIdx.x & 63;
  const int wid  = threadIdx.x >> 6;
  const int wm = (wid >> 1) * 64, wn = (wid & 1) * 64;
  const int lr = lane & 15, lk = lane >> 4;
  #pragma unroll
  for (int mi = 0; mi < 4; ++mi) {
    #pragma unroll
    for (int ni = 0; ni < 4; ++ni) {
      int col = n0 + wn + ni*16 + lr;
      float bv = bias[col];
      #pragma unroll
      for (int j = 0; j < 4; ++j) {
        int row = m0 + wm + mi*16 + lk*4 + j;
        out[(size_t)row*D_MODEL + col] = acc[mi][ni][j] + bv;
      }
    }
  }
}

// ---------------- Flash attention (causal), 4 waves x 16 q-rows, LPT + backfill ----
// No-max softmax (exp2-domain, pre-scaled Q); P = raw v_exp_f32(s).
__global__ __launch_bounds__(256) void k_attn(const __bf16* __restrict__ q,
                                              const __bf16* __restrict__ k,
                                              const __bf16* __restrict__ vt,
                                              __bf16* __restrict__ out) {
  __shared__ __align__(16) char lsK[2][8192];
  __shared__ __align__(16) char lsV[2][8192];

  const int tid  = threadIdx.x;
  const int lane = tid & 63;
  const int wid  = tid >> 6;
  const int lr   = lane & 15;
  const int lk   = lane >> 4;

  const int bid  = blockIdx.x;
  const int qi64 = 31 - bid / (BATCH*NH);
  const int bh   = bid % (BATCH*NH);
  const int b    = bh / NH, h = bh - b*NH;
  const int q0w  = qi64*64 + wid*16;
  const int nt   = qi64 + 1;

  const __bf16* qh = q + (size_t)bh*SEQ*DKH;
  const char*   kB = (const char*)(k  + (size_t)bh*SEQ*DKH);
  const char*   vB = (const char*)(vt + (size_t)bh*DKH*SEQ);

  bf16x8 bq[2];
  #pragma unroll
  for (int c = 0; c < 2; ++c)
    bq[c] = *(const bf16x8*)(qh + (size_t)(q0w + lr)*DKH + c*32 + lk*8);

  bf16x8 ones;
  #pragma unroll
  for (int i = 0; i < 8; ++i) ones[i] = (__bf16)1.0f;
  const f32x4 Z4 = {0.f, 0.f, 0.f, 0.f};

  const int offB = lr*128 + ((lk*16) ^ ((lr & 7) << 4));

  f32x4 o[4];
  #pragma unroll
  for (int df = 0; df < 4; ++df) { f32x4 z = {0.f,0.f,0.f,0.f}; o[df] = z; }
  f32x4 o_l = {0.f, 0.f, 0.f, 0.f};

  auto stage = [&](int buf, int kv0) {
    #pragma unroll
    for (int c = 0; c < 2; ++c) {
      int lb   = (wid*2 + c)*1024 + lane*16;
      int row  = lb >> 7;
      int colb = (lb & 127) ^ ((row & 7) << 4);
      __builtin_amdgcn_global_load_lds(
        (const __attribute__((address_space(1))) void*)(kB + (size_t)(kv0 + row)*128 + colb),
        (__attribute__((address_space(3))) void*)(lsK[buf] + (wid*2 + c)*1024), 16, 0, 0);
      __builtin_amdgcn_global_load_lds(
        (const __attribute__((address_space(1))) void*)(vB + (size_t)row*(SEQ*2) + (size_t)kv0*2 + colb),
        (__attribute__((address_space(3))) void*)(lsV[buf] + (wid*2 + c)*1024), 16, 0, 0);
    }
  };

  stage(0, 0);
  __syncthreads();
  int cur = 0;

  for (int t = 0; t < nt; ++t) {
    const int kv0 = t * 64;
    if (t + 1 < nt) stage(cur ^ 1, kv0 + 64);

    {
      const char* kp0 = lsK[cur] + offB;
      const char* kp1 = lsK[cur] + (offB ^ 64);
      const char* vp0 = lsV[cur] + offB;
      const char* vp1 = lsV[cur] + (offB ^ 64);

      f32x4 sc[4];
      __builtin_amdgcn_s_setprio(1);
      #pragma unroll
      for (int n = 0; n < 4; ++n) {
        bf16x8 ak0 = *(const bf16x8*)(kp0 + n*2048);
        bf16x8 ak1 = *(const bf16x8*)(kp1 + n*2048);
        sc[n] = __builtin_amdgcn_mfma_f32_16x16x32_bf16(ak0, bq[0], Z4, 0, 0, 0);
        sc[n] = __builtin_amdgcn_mfma_f32_16x16x32_bf16(ak1, bq[1], sc[n], 0, 0, 0);
      }
      __builtin_amdgcn_s_setprio(0);
      if (kv0 + 63 > q0w) {
        int qrow = q0w + lr;
        #pragma unroll
        for (int n = 0; n < 4; ++n) {
          int kvb = kv0 + n*16 + lk*4;
          #pragma unroll
          for (int j = 0; j < 4; ++j)
            if (kvb + j > qrow) sc[n][j] = -1e30f;
        }
      }
      bf16x8 pa[2];
      #pragma unroll
      for (int n = 0; n < 4; ++n)
        #pragma unroll
        for (int j = 0; j < 4; ++j)
          pa[n >> 1][((n & 1) << 2) | j] = (__bf16)fast_exp2(sc[n][j]);
      __builtin_amdgcn_s_setprio(1);
      o_l = __builtin_amdgcn_mfma_f32_16x16x32_bf16(pa[0], ones, o_l, 0, 0, 0);
      o_l = __builtin_amdgcn_mfma_f32_16x16x32_bf16(pa[1], ones, o_l, 0, 0, 0);
      #pragma unroll
      for (int df = 0; df < 4; ++df) {
        bf16x8 bv0 = *(const bf16x8*)(vp0 + df*2048);
        bf16x8 bv1 = *(const bf16x8*)(vp1 + df*2048);
        o[df] = __builtin_amdgcn_mfma_f32_16x16x32_bf16(pa[0], bv0, o[df], 0, 0, 0);
        o[df] = __builtin_amdgcn_mfma_f32_16x16x32_bf16(pa[1], bv1, o[df], 0, 0, 0);
      }
      __builtin_amdgcn_s_setprio(0);
    }
    __syncthreads();
    cur ^= 1;
  }

  float invl[4];
  #pragma unroll
  for (int j = 0; j < 4; ++j) invl[j] = 1.0f / o_l[j];
  #pragma unroll
  for (int df = 0; df < 4; ++df) {
    int d = df*16 + lr;
    #pragma unroll
    for (int j = 0; j < 4; ++j) {
      int ss = q0w + lk*4 + j;
      out[((size_t)b*SEQ + ss)*D_MODEL + h*DKH + d] = (__bf16)(o[df][j] * invl[j]);
    }
  }
}

// ---------------- launch ----------------
extern "C" void kernel_launch(void* const* d_in, const int* in_sizes, int n_in,
                              void* d_out, int out_size, void* d_ws, size_t ws_size,
                              hipStream_t stream) {
  const float* x    = (const float*)d_in[0];
  /* d_in[1] = causal mask, implemented analytically */
  const float* Wqkv = (const float*)d_in[2];
  const float* bqkv = (const float*)d_in[3];
  const float* Wout = (const float*)d_in[4];
  const float* bout = (const float*)d_in[5];
  float* out = (float*)d_out;

  char* w = (char*)d_ws;
  __bf16* xb    = (__bf16*)w; w += (size_t)ROWS*D_MODEL*2;
  __bf16* wqkvT = (__bf16*)w; w += (size_t)N_QKV*D_MODEL*2;
  __bf16* woutT = (__bf16*)w; w += (size_t)D_MODEL*D_MODEL*2;
  __bf16* qb    = (__bf16*)w; w += (size_t)BATCH*NH*SEQ*DKH*2;
  __bf16* kb    = (__bf16*)w; w += (size_t)BATCH*NH*SEQ*DKH*2;
  __bf16* vtb   = (__bf16*)w; w += (size_t)BATCH*NH*SEQ*DKH*2;
  __bf16* attnb = (__bf16*)w; w += (size_t)ROWS*D_MODEL*2;

  const int NB_T = (N_QKV/32)*(D_MODEL/32) + (D_MODEL/32)*(D_MODEL/32);
  k_convert<<<(ROWS*D_MODEL/4 + 255)/256, 256, 0, stream>>>(x, xb, ROWS*D_MODEL);
  k_transpose2<<<NB_T, dim3(32, 8), 0, stream>>>(Wqkv, wqkvT, Wout, woutT);
  k_gemm_qkv<<<dim3(N_QKV/128, ROWS/128), 256, 0, stream>>>(xb, wqkvT, bqkv, qb, kb, vtb);
  k_attn<<<32*BATCH*NH, 256, 0, stream>>>(qb, kb, vtb, attnb);
  k_gemm_out<<<dim3(D_MODEL/128, ROWS/128), 256, 0, stream>>>(attnb, woutT, bout, out);
}

// Round 22
// 124.633 us; speedup vs baseline: 1.1619x; 1.0146x over previous
//
#include <hip/hip_runtime.h>

typedef __bf16 bf16x8 __attribute__((ext_vector_type(8)));
typedef __bf16 bf16x4 __attribute__((ext_vector_type(4)));
typedef float f32x4 __attribute__((ext_vector_type(4)));

#define D_MODEL 768
#define NH 12
#define DKH 64
#define BATCH 4
#define SEQ 2048
#define ROWS (BATCH*SEQ)   /* 8192 */
#define N_QKV (3*D_MODEL)  /* 2304 */
#define QSCALE 0.18033688f /* 0.125 * log2(e): folds softmax scale + exp2 domain into Q */

// raw v_exp_f32 (scores in [-1e30, ~40] need no ocml denormal guard)
__device__ __forceinline__ float fast_exp2(float x) {
  float r;
  asm("v_exp_f32 %0, %1" : "=v"(r) : "v"(x));
  return r;
}

// ---------------- fused prep: x fp32->bf16 convert + both weight transposes ----------------
// One launch, 256 threads/block. Blocks [0, NB_CV): convert; rest: 32x32 transpose tiles.
#define NB_CV (ROWS*D_MODEL/4/256)                 /* 6144 */
#define NB_T1 ((N_QKV/32)*(D_MODEL/32))            /* 1728 */
#define NB_T2 ((D_MODEL/32)*(D_MODEL/32))          /* 576  */
__global__ void k_prep(const float* __restrict__ x, __bf16* __restrict__ xb,
                       const float* __restrict__ wqkv, __bf16* __restrict__ wqkvT,
                       const float* __restrict__ wout, __bf16* __restrict__ woutT) {
  __shared__ float tile[32][33];
  int bb = blockIdx.x;
  if (bb < NB_CV) {
    int i = (bb * 256 + threadIdx.x) * 4;
    float4 v = *(const float4*)(x + i);
    bf16x4 o4 = {(__bf16)v.x, (__bf16)v.y, (__bf16)v.z, (__bf16)v.w};
    *(bf16x4*)(xb + i) = o4;
    return;
  }
  bb -= NB_CV;
  const float* in; __bf16* out; int R, C, bx, by;
  if (bb < NB_T1) { in = wqkv; out = wqkvT; R = D_MODEL; C = N_QKV;  bx = bb % (N_QKV/32);  by = bb / (N_QKV/32); }
  else { bb -= NB_T1; in = wout; out = woutT; R = D_MODEL; C = D_MODEL; bx = bb % (D_MODEL/32); by = bb / (D_MODEL/32); }
  int c0 = bx * 32, r0 = by * 32;
  int tx = threadIdx.x & 31, ty = threadIdx.x >> 5;   // (32, 8)
  #pragma unroll
  for (int i = 0; i < 4; ++i) {
    int r = ty + i*8;
    tile[r][tx] = in[(size_t)(r0 + r)*C + c0 + tx];
  }
  __syncthreads();
  #pragma unroll
  for (int i = 0; i < 4; ++i) {
    int c = ty + i*8;
    out[(size_t)(c0 + c)*R + r0 + tx] = (__bf16)tile[tx][c];
  }
}

// ================= 128x128 GEMM core: triple-buffer counted-vmcnt =================
__device__ __forceinline__ void gemm_stage(const __bf16* __restrict__ A, int lda,
                                           const __bf16* __restrict__ Bt, int ldb,
                                           int m0, int n0, int kt,
                                           __bf16* lA, __bf16* lB) {
  const int tid  = threadIdx.x;
  const int lane = tid & 63;
  const int wid  = tid >> 6;
  #pragma unroll
  for (int c = 0; c < 2; ++c) {
    int chunk = wid*2 + c;               // 0..7
    int bo = chunk*1024 + lane*16;
    int m  = bo >> 6;
    int kb = ((bo & 63) ^ (((m >> 1) & 3) << 4)) >> 1;
    __builtin_amdgcn_global_load_lds(
      (const __attribute__((address_space(1))) void*)(A + (size_t)(m0 + m)*lda + kt + kb),
      (__attribute__((address_space(3))) void*)(lA + chunk*512), 16, 0, 0);
    __builtin_amdgcn_global_load_lds(
      (const __attribute__((address_space(1))) void*)(Bt + (size_t)(n0 + m)*ldb + kt + kb),
      (__attribute__((address_space(3))) void*)(lB + chunk*512), 16, 0, 0);
  }
}

__device__ __forceinline__ void gemm_iter(const __bf16* __restrict__ A, int lda,
                                          const __bf16* __restrict__ Bt, int ldb,
                                          int m0, int n0, int t, int NT,
                                          __bf16* lA, __bf16* lB, int BUF, int NBUF,
                                          int wm, int wn, int lr, int lk,
                                          f32x4 acc[4][4]) {
  if (t + 1 < NT) asm volatile("s_waitcnt vmcnt(4)" ::: "memory");
  else            asm volatile("s_waitcnt vmcnt(0)" ::: "memory");
  __builtin_amdgcn_s_barrier();
  asm volatile("" ::: "memory");
  if (t + 2 < NT)
    gemm_stage(A, lda, Bt, ldb, m0, n0, (t+2)*32, lA + NBUF*4096, lB + NBUF*4096);
  const char* cA = (const char*)(lA + BUF*4096);
  const char* cB = (const char*)(lB + BUF*4096);
  bf16x8 af[4], bfr[4];
  #pragma unroll
  for (int i = 0; i < 4; ++i) {
    int ra = wm + i*16 + lr;
    int rb = wn + i*16 + lr;
    af[i]  = *(const bf16x8*)(cA + ra*64 + ((lk*16) ^ (((ra >> 1) & 3) << 4)));
    bfr[i] = *(const bf16x8*)(cB + rb*64 + ((lk*16) ^ (((rb >> 1) & 3) << 4)));
  }
  #pragma unroll
  for (int mi = 0; mi < 4; ++mi)
    #pragma unroll
    for (int ni = 0; ni < 4; ++ni)
      acc[mi][ni] = __builtin_amdgcn_mfma_f32_16x16x32_bf16(af[mi], bfr[ni], acc[mi][ni], 0, 0, 0);
}

__device__ __forceinline__ void gemm_core(const __bf16* __restrict__ A, int lda,
                                          const __bf16* __restrict__ Bt, int ldb,
                                          int K, int m0, int n0,
                                          __bf16* lA, __bf16* lB, f32x4 acc[4][4]) {
  const int lane = threadIdx.x & 63;
  const int wid  = threadIdx.x >> 6;
  const int wm   = (wid >> 1) * 64;
  const int wn   = (wid & 1) * 64;
  const int lr   = lane & 15;
  const int lk   = lane >> 4;
  const int NT   = K >> 5;

  gemm_stage(A, lda, Bt, ldb, m0, n0, 0,  lA,        lB);
  gemm_stage(A, lda, Bt, ldb, m0, n0, 32, lA + 4096, lB + 4096);

  for (int t = 0; t < NT; t += 3) {
    gemm_iter(A, lda, Bt, ldb, m0, n0, t,   NT, lA, lB, 0, 2, wm, wn, lr, lk, acc);
    gemm_iter(A, lda, Bt, ldb, m0, n0, t+1, NT, lA, lB, 1, 0, wm, wn, lr, lk, acc);
    gemm_iter(A, lda, Bt, ldb, m0, n0, t+2, NT, lA, lB, 2, 1, wm, wn, lr, lk, acc);
  }
}

// ---------------- GEMM1: qkv = xb @ WqkvT + bqkv, scatter to Q(scaled),K,V^T(pi) ----------------
__global__ __launch_bounds__(256) void k_gemm_qkv(const __bf16* __restrict__ xb,
                                                  const __bf16* __restrict__ wT,
                                                  const float* __restrict__ bias,
                                                  __bf16* __restrict__ qb,
                                                  __bf16* __restrict__ kb,
                                                  __bf16* __restrict__ vtb) {
  __shared__ __align__(16) __bf16 lA[3*128*32];
  __shared__ __align__(16) __bf16 lB[3*128*32];
  f32x4 acc[4][4];
  #pragma unroll
  for (int i = 0; i < 4; ++i)
    #pragma unroll
    for (int j = 0; j < 4; ++j) { f32x4 z = {0.f,0.f,0.f,0.f}; acc[i][j] = z; }

  const int GX = N_QKV/128;  // 18
  int bid = blockIdx.y * GX + blockIdx.x;
  int cpx = (GX * ROWS/128) >> 3;
  int swz = (bid & 7) * cpx + (bid >> 3);
  const int m0 = (swz / GX) * 128, n0 = (swz % GX) * 128;
  gemm_core(xb, D_MODEL, wT, D_MODEL, D_MODEL, m0, n0, lA, lB, acc);

  const int lane = threadIdx.x & 63;
  const int wid  = threadIdx.x >> 6;
  const int wm = (wid >> 1) * 64, wn = (wid & 1) * 64;
  const int lr = lane & 15, lk = lane >> 4;
  const int tt = n0 / D_MODEL;           // block-uniform q/k/v selector

  if (tt < 2) {
    #pragma unroll
    for (int mi = 0; mi < 4; ++mi) {
      #pragma unroll
      for (int ni = 0; ni < 4; ++ni) {
        int col = n0 + wn + ni*16 + lr;
        int r2  = col - tt*D_MODEL;
        int hh  = r2 >> 6, dk = r2 & 63;
        float bv = bias[col];
        #pragma unroll
        for (int j = 0; j < 4; ++j) {
          int row = m0 + wm + mi*16 + lk*4 + j;
          int bb = row >> 11, ss = row & 2047;
          float fv = acc[mi][ni][j] + bv;
          if (tt == 0) qb[(((size_t)bb*NH + hh)*SEQ + ss)*DKH + dk] = (__bf16)(fv * QSCALE);
          else         kb[(((size_t)bb*NH + hh)*SEQ + ss)*DKH + dk] = (__bf16)fv;
        }
      }
    }
  } else {
    // V: per-wave 8KB LDS patch, then pi-folded transposed read-back.
    __syncthreads();   // all waves past their last tile-buf reads
    __bf16* patch = (wid < 2 ? lA : lB) + (wid & 1)*4096;
    #pragma unroll
    for (int ni = 0; ni < 4; ++ni) {
      int cl = ni*16 + lr;
      float bv = bias[n0 + wn + cl];
      int sw2 = (cl & 7) << 4;
      #pragma unroll
      for (int mi = 0; mi < 4; ++mi) {
        bf16x4 v4;
        #pragma unroll
        for (int j = 0; j < 4; ++j) v4[j] = (__bf16)(acc[mi][ni][j] + bv);
        *(bf16x4*)((char*)patch + ((cl*128 + (mi*16 + lk*4)*2) ^ sw2)) = v4;
      }
    }
    int hh   = (n0 + wn - 2*D_MODEL) >> 6;   // wave-uniform
    int bb   = m0 >> 11;
    int ssG  = (m0 & 2047) + wm;             // granule-aligned base
    int dk_h = lane >> 4;                    // 0..3
    int pb   = (lane & 15) * 4;              // p = pb..pb+3
    int g    = pb >> 5;                      // granule 0/1
    int tq   = (pb >> 2) & 7;
    int rwb  = g*32 + 16*(tq & 1) + 4*(tq >> 1);   // source kv offset (pi)
    __bf16* vout = vtb + (((size_t)bb*NH + hh)*DKH)*SEQ + ssG + pb;
    #pragma unroll
    for (int r = 0; r < 16; ++r) {
      int dk = r*4 + dk_h;
      bf16x4 v4 = *(const bf16x4*)((const char*)patch + ((dk*128 + rwb*2) ^ ((dk & 7) << 4)));
      *(bf16x4*)(vout + (size_t)dk*SEQ) = v4;
    }
  }
}

// ---------------- GEMM3: out = attn @ WoutT + bout (fp32 out) ----------------
__global__ __launch_bounds__(256) void k_gemm_out(const __bf16* __restrict__ ab,
                                                  const __bf16* __restrict__ wT,
                                                  const float* __restrict__ bias,
                                                  float* __restrict__ out) {
  __shared__ __align__(16) __bf16 lA[3*128*32];
  __shared__ __align__(16) __bf16 lB[3*128*32];
  f32x4 acc[4][4];
  #pragma unroll
  for (int i = 0; i < 4; ++i)
    #pragma unroll
    for (int j = 0; j < 4; ++j) { f32x4 z = {0.f,0.f,0.f,0.f}; acc[i][j] = z; }

  const int GX = D_MODEL/128;  // 6
  int bid = blockIdx.y * GX + blockIdx.x;
  int cpx = (GX * ROWS/128) >> 3;
  int swz = (bid & 7) * cpx + (bid >> 3);
  const int m0 = (swz / GX) * 128, n0 = (swz % GX) * 128;
  gemm_core(ab, D_MODEL, wT, D_MODEL, D_MODEL, m0, n0, lA, lB, acc);

  const int lane = threadIdx.x & 63;
  const int wid  = threadIdx.x >> 6;
  const int wm = (wid >> 1) * 64, wn = (wid & 1) * 64;
  const int lr = lane & 15, lk = lane >> 4;
  #pragma unroll
  for (int mi = 0; mi < 4; ++mi) {
    #pragma unroll
    for (int ni = 0; ni < 4; ++ni) {
      int col = n0 + wn + ni*16 + lr;
      float bv = bias[col];
      #pragma unroll
      for (int j = 0; j < 4; ++j) {
        int row = m0 + wm + mi*16 + lk*4 + j;
        out[(size_t)row*D_MODEL + col] = acc[mi][ni][j] + bv;
      }
    }
  }
}

// ---------------- Flash attention (causal), 4 waves x 16 q-rows, LPT + backfill ----
// No-max softmax (exp2-domain, pre-scaled Q); P = raw v_exp_f32(s).
__global__ __launch_bounds__(256) void k_attn(const __bf16* __restrict__ q,
                                              const __bf16* __restrict__ k,
                                              const __bf16* __restrict__ vt,
                                              __bf16* __restrict__ out) {
  __shared__ __align__(16) char lsK[2][8192];
  __shared__ __align__(16) char lsV[2][8192];

  const int tid  = threadIdx.x;
  const int lane = tid & 63;
  const int wid  = tid >> 6;
  const int lr   = lane & 15;
  const int lk   = lane >> 4;

  const int bid  = blockIdx.x;
  const int qi64 = 31 - bid / (BATCH*NH);
  const int bh   = bid % (BATCH*NH);
  const int b    = bh / NH, h = bh - b*NH;
  const int q0w  = qi64*64 + wid*16;
  const int nt   = qi64 + 1;

  const __bf16* qh = q + (size_t)bh*SEQ*DKH;
  const char*   kB = (const char*)(k  + (size_t)bh*SEQ*DKH);
  const char*   vB = (const char*)(vt + (size_t)bh*DKH*SEQ);

  bf16x8 bq[2];
  #pragma unroll
  for (int c = 0; c < 2; ++c)
    bq[c] = *(const bf16x8*)(qh + (size_t)(q0w + lr)*DKH + c*32 + lk*8);

  bf16x8 ones;
  #pragma unroll
  for (int i = 0; i < 8; ++i) ones[i] = (__bf16)1.0f;
  const f32x4 Z4 = {0.f, 0.f, 0.f, 0.f};

  const int offB = lr*128 + ((lk*16) ^ ((lr & 7) << 4));

  f32x4 o[4];
  #pragma unroll
  for (int df = 0; df < 4; ++df) { f32x4 z = {0.f,0.f,0.f,0.f}; o[df] = z; }
  f32x4 o_l = {0.f, 0.f, 0.f, 0.f};

  auto stage = [&](int buf, int kv0) {
    #pragma unroll
    for (int c = 0; c < 2; ++c) {
      int lb   = (wid*2 + c)*1024 + lane*16;
      int row  = lb >> 7;
      int colb = (lb & 127) ^ ((row & 7) << 4);
      __builtin_amdgcn_global_load_lds(
        (const __attribute__((address_space(1))) void*)(kB + (size_t)(kv0 + row)*128 + colb),
        (__attribute__((address_space(3))) void*)(lsK[buf] + (wid*2 + c)*1024), 16, 0, 0);
      __builtin_amdgcn_global_load_lds(
        (const __attribute__((address_space(1))) void*)(vB + (size_t)row*(SEQ*2) + (size_t)kv0*2 + colb),
        (__attribute__((address_space(3))) void*)(lsV[buf] + (wid*2 + c)*1024), 16, 0, 0);
    }
  };

  stage(0, 0);
  __syncthreads();
  int cur = 0;

  for (int t = 0; t < nt; ++t) {
    const int kv0 = t * 64;
    if (t + 1 < nt) stage(cur ^ 1, kv0 + 64);

    {
      const char* kp0 = lsK[cur] + offB;
      const char* kp1 = lsK[cur] + (offB ^ 64);
      const char* vp0 = lsV[cur] + offB;
      const char* vp1 = lsV[cur] + (offB ^ 64);

      f32x4 sc[4];
      __builtin_amdgcn_s_setprio(1);
      #pragma unroll
      for (int n = 0; n < 4; ++n) {
        bf16x8 ak0 = *(const bf16x8*)(kp0 + n*2048);
        bf16x8 ak1 = *(const bf16x8*)(kp1 + n*2048);
        sc[n] = __builtin_amdgcn_mfma_f32_16x16x32_bf16(ak0, bq[0], Z4, 0, 0, 0);
        sc[n] = __builtin_amdgcn_mfma_f32_16x16x32_bf16(ak1, bq[1], sc[n], 0, 0, 0);
      }
      __builtin_amdgcn_s_setprio(0);
      if (kv0 + 63 > q0w) {
        int qrow = q0w + lr;
        #pragma unroll
        for (int n = 0; n < 4; ++n) {
          int kvb = kv0 + n*16 + lk*4;
          #pragma unroll
          for (int j = 0; j < 4; ++j)
            if (kvb + j > qrow) sc[n][j] = -1e30f;
        }
      }
      bf16x8 pa[2];
      #pragma unroll
      for (int n = 0; n < 4; ++n)
        #pragma unroll
        for (int j = 0; j < 4; ++j)
          pa[n >> 1][((n & 1) << 2) | j] = (__bf16)fast_exp2(sc[n][j]);
      __builtin_amdgcn_s_setprio(1);
      o_l = __builtin_amdgcn_mfma_f32_16x16x32_bf16(pa[0], ones, o_l, 0, 0, 0);
      o_l = __builtin_amdgcn_mfma_f32_16x16x32_bf16(pa[1], ones, o_l, 0, 0, 0);
      #pragma unroll
      for (int df = 0; df < 4; ++df) {
        bf16x8 bv0 = *(const bf16x8*)(vp0 + df*2048);
        bf16x8 bv1 = *(const bf16x8*)(vp1 + df*2048);
        o[df] = __builtin_amdgcn_mfma_f32_16x16x32_bf16(pa[0], bv0, o[df], 0, 0, 0);
        o[df] = __builtin_amdgcn_mfma_f32_16x16x32_bf16(pa[1], bv1, o[df], 0, 0, 0);
      }
      __builtin_amdgcn_s_setprio(0);
    }
    __syncthreads();
    cur ^= 1;
  }

  float invl[4];
  #pragma unroll
  for (int j = 0; j < 4; ++j) invl[j] = 1.0f / o_l[j];
  #pragma unroll
  for (int df = 0; df < 4; ++df) {
    int d = df*16 + lr;
    #pragma unroll
    for (int j = 0; j < 4; ++j) {
      int ss = q0w + lk*4 + j;
      out[((size_t)b*SEQ + ss)*D_MODEL + h*DKH + d] = (__bf16)(o[df][j] * invl[j]);
    }
  }
}

// ---------------- launch ----------------
extern "C" void kernel_launch(void* const* d_in, const int* in_sizes, int n_in,
                              void* d_out, int out_size, void* d_ws, size_t ws_size,
                              hipStream_t stream) {
  const float* x    = (const float*)d_in[0];
  /* d_in[1] = causal mask, implemented analytically */
  const float* Wqkv = (const float*)d_in[2];
  const float* bqkv = (const float*)d_in[3];
  const float* Wout = (const float*)d_in[4];
  const float* bout = (const float*)d_in[5];
  float* out = (float*)d_out;

  char* w = (char*)d_ws;
  __bf16* xb    = (__bf16*)w; w += (size_t)ROWS*D_MODEL*2;
  __bf16* wqkvT = (__bf16*)w; w += (size_t)N_QKV*D_MODEL*2;
  __bf16* woutT = (__bf16*)w; w += (size_t)D_MODEL*D_MODEL*2;
  __bf16* qb    = (__bf16*)w; w += (size_t)BATCH*NH*SEQ*DKH*2;
  __bf16* kb    = (__bf16*)w; w += (size_t)BATCH*NH*SEQ*DKH*2;
  __bf16* vtb   = (__bf16*)w; w += (size_t)BATCH*NH*SEQ*DKH*2;
  __bf16* attnb = (__bf16*)w; w += (size_t)ROWS*D_MODEL*2;

  k_prep<<<NB_CV + NB_T1 + NB_T2, 256, 0, stream>>>(x, xb, Wqkv, wqkvT, Wout, woutT);
  k_gemm_qkv<<<dim3(N_QKV/128, ROWS/128), 256, 0, stream>>>(xb, wqkvT, bqkv, qb, kb, vtb);
  k_attn<<<32*BATCH*NH, 256, 0, stream>>>(qb, kb, vtb, attnb);
  k_gemm_out<<<dim3(D_MODEL/128, ROWS/128), 256, 0, stream>>>(attnb, woutT, bout, out);
}